// Round 1
// baseline (9076.247 us; speedup 1.0000x reference)
//
#include <hip/hip_runtime.h>

#define NNODES 20000
#define NEDGES 640000
#define NGRAPHS 16
#define NO     256
#define NNF    58
#define EMBD   512
#define NL     28

__device__ __forceinline__ float fast_tanh(float x) {
    float e = __expf(2.0f * x);
    return 1.0f - 2.0f / (e + 1.0f);
}

// ---------------- CSR build (once per launch) ----------------
__global__ __launch_bounds__(256) void k_hist(const int* __restrict__ dst, int* __restrict__ counts) {
    int e = blockIdx.x * 256 + threadIdx.x;
    if (e < NEDGES) atomicAdd(&counts[dst[e]], 1);
}

__global__ __launch_bounds__(256) void k_scan(const int* __restrict__ counts, int* __restrict__ offs) {
    __shared__ int part[256];
    int t = threadIdx.x;
    const int CH = (NNODES + 255) / 256;  // 79
    int base = t * CH;
    int s = 0;
    for (int i = 0; i < CH; ++i) { int idx = base + i; if (idx < NNODES) s += counts[idx]; }
    part[t] = s;
    __syncthreads();
    if (t == 0) { int acc = 0; for (int i = 0; i < 256; ++i) { int v = part[i]; part[i] = acc; acc += v; } }
    __syncthreads();
    int acc = part[t];
    for (int i = 0; i < CH; ++i) { int idx = base + i; if (idx < NNODES) { offs[idx] = acc; acc += counts[idx]; } }
    if (t == 255) offs[NNODES] = acc;
}

__global__ __launch_bounds__(256) void k_copy(const int* __restrict__ a, int* __restrict__ b, int n) {
    int i = blockIdx.x * 256 + threadIdx.x;
    if (i < n) b[i] = a[i];
}

__global__ __launch_bounds__(256) void k_fill(const int* __restrict__ src, const int* __restrict__ dst,
                                              const float* __restrict__ ef, int* __restrict__ cursor,
                                              int* __restrict__ srcp, float* __restrict__ efp) {
    int e = blockIdx.x * 256 + threadIdx.x;
    if (e < NEDGES) {
        int d = dst[e];
        int pos = atomicAdd(&cursor[d], 1);
        srcp[pos] = src[e];
        efp[pos]  = ef[e];
    }
}

// ---------------- weight precompute ----------------
// Wcat layout: [NL][768][NO] row-major (layer 0 uses only first NNF cols).
// rows 0..255 = Wn; 256..511 = (Wm*diag(We))@Wn; 512..767 = (Wm*diag(be))@Wn
// bcat: matching biases (bn; (Wm*We)@bn; (Wm*be)@bn + bm)
__global__ __launch_bounds__(256) void k_prep(
    const float* __restrict__ Wn0, const float* __restrict__ bn0,
    const float* __restrict__ We0, const float* __restrict__ be0,
    const float* __restrict__ Wm0, const float* __restrict__ bm0,
    const float* __restrict__ Wn,  const float* __restrict__ bn,
    const float* __restrict__ We,  const float* __restrict__ be,
    const float* __restrict__ Wm,  const float* __restrict__ bm,
    float* __restrict__ Wcat, float* __restrict__ bcat) {
    int l = blockIdx.x / 768;
    int r = blockIdx.x % 768;
    int k = threadIdx.x;  // 0..255
    const float *wn, *bnv, *wev, *bev, *wm, *bmv;
    int K;
    if (l == 0) { wn = Wn0; bnv = bn0; wev = We0; bev = be0; wm = Wm0; bmv = bm0; K = NNF; }
    else {
        int j = l - 1;
        wn = Wn + (size_t)j * NO * NO; bnv = bn + j * NO;
        wev = We + j * NO;             bev = be + j * NO;
        wm = Wm + (size_t)j * NO * NO; bmv = bm + j * NO;
        K = NO;
    }
    float* Wout = Wcat + ((size_t)l * 768 + r) * NO;
    float* bout = bcat + l * 768 + r;
    if (r < NO) {
        if (k < K) Wout[k] = wn[(size_t)r * K + k];
        else       Wout[k] = 0.f;
        if (k == 0) *bout = bnv[r];
        return;
    }
    int i = (r < 512) ? r - 256 : r - 512;
    const float* scale = (r < 512) ? wev : bev;
    __shared__ float coeff[NO];
    coeff[k] = wm[(size_t)i * NO + k] * scale[k];
    __syncthreads();
    float acc = 0.f;
    if (k < K) {
        for (int j = 0; j < NO; ++j) acc += coeff[j] * wn[(size_t)j * K + k];
        Wout[k] = acc;
    } else Wout[k] = 0.f;
    if (k == 0) {
        float b = 0.f;
        for (int j = 0; j < NO; ++j) b += coeff[j] * bnv[j];
        if (r >= 512) b += bmv[i];
        *bout = b;
    }
}

// ---------------- fused layer GEMM: C[M x 768] = A[M x K] @ W[768 x K].T + bias ----------------
#define BM 64
#define BN 64
#define BK 16
__global__ __launch_bounds__(256) void k_gemm(const float* __restrict__ A, const float* __restrict__ W,
                                              const float* __restrict__ bias, float* __restrict__ C,
                                              int M, int K, int lda) {
    __shared__ float sA[BK][BM + 4];
    __shared__ float sB[BK][BN + 4];
    int bn0 = blockIdx.x * BN;
    int bm0 = blockIdx.y * BM;
    int t = threadIdx.x;
    int tx = t % 16, ty = t / 16;
    float acc[4][4] = {};
    for (int k0 = 0; k0 < K; k0 += BK) {
        for (int i = 0; i < 4; ++i) {
            int e = t + 256 * i;
            int r = e / BK, c = e % BK;
            int gr = bm0 + r, gc = k0 + c;
            sA[c][r] = (gr < M && gc < K) ? A[(size_t)gr * lda + gc] : 0.f;
        }
        for (int i = 0; i < 4; ++i) {
            int e = t + 256 * i;
            int n = e / BK, c = e % BK;
            int gc = k0 + c;
            sB[c][n] = (gc < K) ? W[(size_t)(bn0 + n) * NO + gc] : 0.f;
        }
        __syncthreads();
        for (int kk = 0; kk < BK; ++kk) {
            float a[4], b[4];
            for (int i = 0; i < 4; ++i) a[i] = sA[kk][ty * 4 + i];
            for (int j = 0; j < 4; ++j) b[j] = sB[kk][tx * 4 + j];
            for (int i = 0; i < 4; ++i)
                for (int j = 0; j < 4; ++j) acc[i][j] += a[i] * b[j];
        }
        __syncthreads();
    }
    for (int i = 0; i < 4; ++i) {
        int gr = bm0 + ty * 4 + i;
        if (gr >= M) continue;
        for (int j = 0; j < 4; ++j) {
            int gn = bn0 + tx * 4 + j;
            C[(size_t)gr * 768 + gn] = acc[i][j] + bias[gn];
        }
    }
}

// ---------------- edge aggregation (CSR by dst, no atomics) ----------------
// huv row layout per node: [hn(256) | u(256) | v(256)]
__global__ __launch_bounds__(64) void k_edge(const float* __restrict__ huv, const int* __restrict__ offs,
                                             const int* __restrict__ srcp, const float* __restrict__ efp,
                                             float* __restrict__ hout) {
    int n = blockIdx.x;
    int t = threadIdx.x;       // 0..63
    int c = t * 4;
    int e0 = offs[n], e1 = offs[n + 1];
    float a0 = 0.f, a1 = 0.f, a2 = 0.f, a3 = 0.f;
    for (int e = e0; e < e1; ++e) {
        int s = srcp[e];
        float ef = efp[e];
        const float* base = huv + (size_t)s * 768;
        float4 u4 = *(const float4*)(base + 256 + c);
        float4 v4 = *(const float4*)(base + 512 + c);
        a0 += fast_tanh(ef * u4.x + v4.x);
        a1 += fast_tanh(ef * u4.y + v4.y);
        a2 += fast_tanh(ef * u4.z + v4.z);
        a3 += fast_tanh(ef * u4.w + v4.w);
    }
    float4 hn4 = *(const float4*)(huv + (size_t)n * 768 + c);
    float4 o;
    o.x = hn4.x + a0; o.y = hn4.y + a1; o.z = hn4.z + a2; o.w = hn4.w + a3;
    *(float4*)(hout + (size_t)n * NO + c) = o;
}

// ---------------- pooling ----------------
__global__ __launch_bounds__(256) void k_pool(const float* __restrict__ h, const int* __restrict__ batch,
                                              float* __restrict__ sums, float* __restrict__ cnts) {
    int n = blockIdx.x;
    int t = threadIdx.x;
    int g = batch[n];
    atomicAdd(&sums[(size_t)g * NO + t], h[(size_t)n * NO + t]);
    if (t == 0) atomicAdd(&cnts[g], 1.0f);
}

__global__ __launch_bounds__(512) void k_final(const float* __restrict__ sums, const float* __restrict__ cnts,
                                               const float* __restrict__ Wlin, const float* __restrict__ blin,
                                               float* __restrict__ out) {
    int g = blockIdx.x;   // 16
    int t = threadIdx.x;  // 512
    __shared__ float m[NO];
    if (t < NO) m[t] = sums[(size_t)g * NO + t] / cnts[g];
    __syncthreads();
    float acc = blin[t];
    for (int k = 0; k < NO; ++k) acc += m[k] * Wlin[(size_t)t * NO + k];
    out[(size_t)g * EMBD + t] = acc;
}

extern "C" void kernel_launch(void* const* d_in, const int* in_sizes, int n_in,
                              void* d_out, int out_size, void* d_ws, size_t ws_size,
                              hipStream_t stream) {
    const float* x     = (const float*)d_in[0];
    const int*   ei    = (const int*)d_in[1];
    const float* ef    = (const float*)d_in[2];
    const int*   batch = (const int*)d_in[3];
    const float* Wn0 = (const float*)d_in[4];
    const float* bn0 = (const float*)d_in[5];
    const float* We0 = (const float*)d_in[6];
    const float* be0 = (const float*)d_in[7];
    const float* Wm0 = (const float*)d_in[8];
    const float* bm0 = (const float*)d_in[9];
    const float* Wn  = (const float*)d_in[10];
    const float* bn  = (const float*)d_in[11];
    const float* We  = (const float*)d_in[12];
    const float* be  = (const float*)d_in[13];
    const float* Wm  = (const float*)d_in[14];
    const float* bm  = (const float*)d_in[15];
    const float* Wlin = (const float*)d_in[16];
    const float* blin = (const float*)d_in[17];
    float* out = (float*)d_out;

    // workspace carve (256B aligned slices)
    char* p = (char*)d_ws;
    auto carve = [&](size_t bytes) { char* q = p; p += (bytes + 255) & ~(size_t)255; return q; };
    float* h     = (float*)carve((size_t)NNODES * NO * 4);        // 20.48 MB
    float* huv   = (float*)carve((size_t)NNODES * 768 * 4);       // 61.44 MB
    float* Wcat  = (float*)carve((size_t)NL * 768 * NO * 4);      // 22.02 MB
    float* bcat  = (float*)carve((size_t)NL * 768 * 4);
    int*   offs  = (int*)carve((size_t)(NNODES + 1) * 4);
    int*   cur   = (int*)carve((size_t)NNODES * 4);
    int*   srcp  = (int*)carve((size_t)NEDGES * 4);
    float* efp   = (float*)carve((size_t)NEDGES * 4);
    float* sums  = (float*)carve((size_t)NGRAPHS * NO * 4 + NGRAPHS * 4);  // sums + cnts contiguous
    float* cnts  = sums + NGRAPHS * NO;

    const int* src = ei;
    const int* dst = ei + NEDGES;

    // CSR build
    hipMemsetAsync(cur, 0, (size_t)NNODES * 4, stream);
    k_hist<<<NEDGES / 256, 256, 0, stream>>>(dst, cur);
    k_scan<<<1, 256, 0, stream>>>(cur, offs);
    k_copy<<<(NNODES + 255) / 256, 256, 0, stream>>>(offs, cur, NNODES);
    k_fill<<<NEDGES / 256, 256, 0, stream>>>(src, dst, ef, cur, srcp, efp);

    // composed per-layer weights
    k_prep<<<NL * 768, 256, 0, stream>>>(Wn0, bn0, We0, be0, Wm0, bm0,
                                         Wn, bn, We, be, Wm, bm, Wcat, bcat);

    // 28 layers
    for (int l = 0; l < NL; ++l) {
        const float* Ain = (l == 0) ? x : h;
        int K   = (l == 0) ? NNF : NO;
        int lda = K;
        dim3 grid(768 / BN, (NNODES + BM - 1) / BM);
        k_gemm<<<grid, 256, 0, stream>>>(Ain, Wcat + (size_t)l * 768 * NO, bcat + (size_t)l * 768,
                                         huv, NNODES, K, lda);
        k_edge<<<NNODES, 64, 0, stream>>>(huv, offs, srcp, efp, h);
    }

    // mean-pool (linearity: pool h, then tiny final GEMM)
    hipMemsetAsync(sums, 0, ((size_t)NGRAPHS * NO + NGRAPHS) * 4, stream);
    k_pool<<<NNODES, 256, 0, stream>>>(h, batch, sums, cnts);
    k_final<<<NGRAPHS, 512, 0, stream>>>(sums, cnts, Wlin, blin, out);
}

// Round 2
// 8252.179 us; speedup vs baseline: 1.0999x; 1.0999x over previous
//
#include <hip/hip_runtime.h>

#define NNODES 20000
#define NEDGES 640000
#define NGRAPHS 16
#define NO     256
#define NNF    58
#define KPAD   64
#define EMBD   512
#define NL     28

__device__ __forceinline__ float fast_tanh(float x) {
    float e = __expf(2.0f * x);
    return 1.0f - 2.0f / (e + 1.0f);
}

// ---------------- CSR build (once per launch) ----------------
__global__ __launch_bounds__(256) void k_hist(const int* __restrict__ dst, int* __restrict__ counts) {
    int e = blockIdx.x * 256 + threadIdx.x;
    if (e < NEDGES) atomicAdd(&counts[dst[e]], 1);
}

__global__ __launch_bounds__(256) void k_scan(const int* __restrict__ counts, int* __restrict__ offs) {
    __shared__ int part[256];
    int t = threadIdx.x;
    const int CH = (NNODES + 255) / 256;  // 79
    int base = t * CH;
    int s = 0;
    for (int i = 0; i < CH; ++i) { int idx = base + i; if (idx < NNODES) s += counts[idx]; }
    part[t] = s;
    __syncthreads();
    if (t == 0) { int acc = 0; for (int i = 0; i < 256; ++i) { int v = part[i]; part[i] = acc; acc += v; } }
    __syncthreads();
    int acc = part[t];
    for (int i = 0; i < CH; ++i) { int idx = base + i; if (idx < NNODES) { offs[idx] = acc; acc += counts[idx]; } }
    if (t == 255) offs[NNODES] = acc;
}

__global__ __launch_bounds__(256) void k_copy(const int* __restrict__ a, int* __restrict__ b, int n) {
    int i = blockIdx.x * 256 + threadIdx.x;
    if (i < n) b[i] = a[i];
}

__global__ __launch_bounds__(256) void k_fill(const int* __restrict__ src, const int* __restrict__ dst,
                                              const float* __restrict__ ef, int* __restrict__ cursor,
                                              int* __restrict__ srcp, float* __restrict__ efp) {
    int e = blockIdx.x * 256 + threadIdx.x;
    if (e < NEDGES) {
        int d = dst[e];
        int pos = atomicAdd(&cursor[d], 1);
        srcp[pos] = src[e];
        efp[pos]  = ef[e];
    }
}

// ---------------- layer-0 input pad: [20000][58] -> [20000][64] ----------------
__global__ __launch_bounds__(256) void k_padx(const float* __restrict__ x, float* __restrict__ xpad) {
    int i = blockIdx.x * 256 + threadIdx.x;
    if (i < NNODES * KPAD) {
        int r = i >> 6, c = i & 63;
        xpad[i] = (c < NNF) ? x[r * NNF + c] : 0.f;
    }
}

// ---------------- weight precompute ----------------
// Wcat layout: [NL][768][NO] row-major (layer 0 uses only first NNF cols, rest zero).
// rows 0..255 = Wn; 256..511 = (Wm*diag(We))@Wn; 512..767 = (Wm*diag(be))@Wn
__global__ __launch_bounds__(256) void k_prep(
    const float* __restrict__ Wn0, const float* __restrict__ bn0,
    const float* __restrict__ We0, const float* __restrict__ be0,
    const float* __restrict__ Wm0, const float* __restrict__ bm0,
    const float* __restrict__ Wn,  const float* __restrict__ bn,
    const float* __restrict__ We,  const float* __restrict__ be,
    const float* __restrict__ Wm,  const float* __restrict__ bm,
    float* __restrict__ Wcat, float* __restrict__ bcat) {
    int l = blockIdx.x / 768;
    int r = blockIdx.x % 768;
    int k = threadIdx.x;  // 0..255
    const float *wn, *bnv, *wev, *bev, *wm, *bmv;
    int K;
    if (l == 0) { wn = Wn0; bnv = bn0; wev = We0; bev = be0; wm = Wm0; bmv = bm0; K = NNF; }
    else {
        int j = l - 1;
        wn = Wn + (size_t)j * NO * NO; bnv = bn + j * NO;
        wev = We + j * NO;             bev = be + j * NO;
        wm = Wm + (size_t)j * NO * NO; bmv = bm + j * NO;
        K = NO;
    }
    float* Wout = Wcat + ((size_t)l * 768 + r) * NO;
    float* bout = bcat + l * 768 + r;
    if (r < NO) {
        if (k < K) Wout[k] = wn[(size_t)r * K + k];
        else       Wout[k] = 0.f;
        if (k == 0) *bout = bnv[r];
        return;
    }
    int i = (r < 512) ? r - 256 : r - 512;
    const float* scale = (r < 512) ? wev : bev;
    __shared__ float coeff[NO];
    coeff[k] = wm[(size_t)i * NO + k] * scale[k];
    __syncthreads();
    float acc = 0.f;
    if (k < K) {
        for (int j = 0; j < NO; ++j) acc += coeff[j] * wn[(size_t)j * K + k];
        Wout[k] = acc;
    } else Wout[k] = 0.f;
    if (k == 0) {
        float b = 0.f;
        for (int j = 0; j < NO; ++j) b += coeff[j] * bnv[j];
        if (r >= 512) b += bmv[i];
        *bout = b;
    }
}

// ---------------- fused layer GEMM: C[M x 768] = A[M x K] @ W[768 x K].T + bias ----------------
// Output row layout (768 floats): [hn(256) | uv interleaved: u_i -> 256+8*(i>>2)+(i&3), v_i -> +4]
#define BM 128
#define BN 64
#define BK 16
__global__ __launch_bounds__(256) void k_gemm(const float* __restrict__ A, const float* __restrict__ W,
                                              const float* __restrict__ bias, float* __restrict__ C,
                                              int M, int K) {
    __shared__ float sA[BK][BM + 4];
    __shared__ float sB[BK][BN + 4];
    int bn0 = blockIdx.x * BN;
    int bm0 = blockIdx.y * BM;
    int t = threadIdx.x;
    int tx = t & 15, ty = t >> 4;
    float acc[8][4] = {};
    for (int k0 = 0; k0 < K; k0 += BK) {
        #pragma unroll
        for (int rep = 0; rep < 2; ++rep) {
            int idx = t + rep * 256;
            int r = idx >> 2, cq = (idx & 3) * 4;
            int gr = bm0 + r;
            float4 a4 = {0.f, 0.f, 0.f, 0.f};
            if (gr < M) a4 = *(const float4*)(A + (size_t)gr * K + k0 + cq);
            sA[cq + 0][r] = a4.x; sA[cq + 1][r] = a4.y; sA[cq + 2][r] = a4.z; sA[cq + 3][r] = a4.w;
        }
        {
            int r = t >> 2, cq = (t & 3) * 4;
            float4 b4 = *(const float4*)(W + (size_t)(bn0 + r) * NO + k0 + cq);
            sB[cq + 0][r] = b4.x; sB[cq + 1][r] = b4.y; sB[cq + 2][r] = b4.z; sB[cq + 3][r] = b4.w;
        }
        __syncthreads();
        #pragma unroll
        for (int kk = 0; kk < BK; ++kk) {
            float a[8], b[4];
            *(float4*)a       = *(const float4*)&sA[kk][ty * 8];
            *(float4*)(a + 4) = *(const float4*)&sA[kk][ty * 8 + 4];
            *(float4*)b       = *(const float4*)&sB[kk][tx * 4];
            #pragma unroll
            for (int i = 0; i < 8; ++i)
                #pragma unroll
                for (int j = 0; j < 4; ++j) acc[i][j] += a[i] * b[j];
        }
        __syncthreads();
    }
    int n0 = bn0 + tx * 4;
    size_t off;
    if (n0 < 256)      off = n0;
    else if (n0 < 512) off = 256 + 8 * ((size_t)(n0 - 256) >> 2);
    else               off = 260 + 8 * ((size_t)(n0 - 512) >> 2);
    float4 bi = *(const float4*)(bias + n0);
    #pragma unroll
    for (int i = 0; i < 8; ++i) {
        int gr = bm0 + ty * 8 + i;
        if (gr >= M) continue;
        float4 o = {acc[i][0] + bi.x, acc[i][1] + bi.y, acc[i][2] + bi.z, acc[i][3] + bi.w};
        *(float4*)(C + (size_t)gr * 768 + off) = o;
    }
}

// ---------------- edge aggregation: wave-per-node, shfl-broadcast edge meta ----------------
__global__ __launch_bounds__(256) void k_edge(const float* __restrict__ huv, const int* __restrict__ offs,
                                              const int* __restrict__ srcp, const float* __restrict__ efp,
                                              float* __restrict__ hout) {
    int wv = threadIdx.x >> 6;
    int lane = threadIdx.x & 63;
    int n = blockIdx.x * 4 + wv;
    int e0 = offs[n], e1 = offs[n + 1];
    float a0 = 0.f, a1 = 0.f, a2 = 0.f, a3 = 0.f;
    for (int eb = e0; eb < e1; eb += 64) {
        int cnt = e1 - eb; if (cnt > 64) cnt = 64;
        int sv = 0; float fv = 0.f;
        if (lane < cnt) { sv = srcp[eb + lane]; fv = efp[eb + lane]; }
        #pragma unroll 4
        for (int i = 0; i < cnt; ++i) {
            int ss = __shfl(sv, i);
            float ff = __shfl(fv, i);
            const float* p = huv + (size_t)ss * 768 + 256 + lane * 8;
            float4 u4 = *(const float4*)p;
            float4 v4 = *(const float4*)(p + 4);
            a0 += fast_tanh(ff * u4.x + v4.x);
            a1 += fast_tanh(ff * u4.y + v4.y);
            a2 += fast_tanh(ff * u4.z + v4.z);
            a3 += fast_tanh(ff * u4.w + v4.w);
        }
    }
    float4 hn4 = *(const float4*)(huv + (size_t)n * 768 + lane * 4);
    float4 o = {hn4.x + a0, hn4.y + a1, hn4.z + a2, hn4.w + a3};
    *(float4*)(hout + (size_t)n * NO + lane * 4) = o;
}

// ---------------- pooling via sorted-batch ranges ----------------
__device__ __forceinline__ int lower_bound_g(const int* __restrict__ batch, int target) {
    int lo = 0, hi = NNODES;
    while (lo < hi) { int mid = (lo + hi) >> 1; if (batch[mid] < target) lo = mid + 1; else hi = mid; }
    return lo;
}

__global__ __launch_bounds__(256) void k_pool2(const float* __restrict__ h, const int* __restrict__ batch,
                                               float* __restrict__ sums) {
    int g = blockIdx.x, chunk = blockIdx.y;
    __shared__ int sh[2];
    if (threadIdx.x < 2) sh[threadIdx.x] = lower_bound_g(batch, g + (int)threadIdx.x);
    __syncthreads();
    int lo = sh[0], hi = sh[1];
    float acc = 0.f;
    for (int r = lo + chunk; r < hi; r += 8)
        acc += h[(size_t)r * NO + threadIdx.x];
    atomicAdd(&sums[g * NO + threadIdx.x], acc);
}

__global__ __launch_bounds__(512) void k_final(const float* __restrict__ sums, const int* __restrict__ batch,
                                               const float* __restrict__ Wlin, const float* __restrict__ blin,
                                               float* __restrict__ out) {
    int g = blockIdx.x, t = threadIdx.x;
    __shared__ int sh[2];
    __shared__ float m[NO];
    if (t < 2) sh[t] = lower_bound_g(batch, g + t);
    __syncthreads();
    float inv = 1.f / (float)(sh[1] - sh[0]);
    if (t < NO) m[t] = sums[g * NO + t] * inv;
    __syncthreads();
    float acc = blin[t];
    for (int k = 0; k < NO; ++k) acc += m[k] * Wlin[(size_t)t * NO + k];
    out[(size_t)g * EMBD + t] = acc;
}

extern "C" void kernel_launch(void* const* d_in, const int* in_sizes, int n_in,
                              void* d_out, int out_size, void* d_ws, size_t ws_size,
                              hipStream_t stream) {
    const float* x     = (const float*)d_in[0];
    const int*   ei    = (const int*)d_in[1];
    const float* ef    = (const float*)d_in[2];
    const int*   batch = (const int*)d_in[3];
    const float* Wn0 = (const float*)d_in[4];
    const float* bn0 = (const float*)d_in[5];
    const float* We0 = (const float*)d_in[6];
    const float* be0 = (const float*)d_in[7];
    const float* Wm0 = (const float*)d_in[8];
    const float* bm0 = (const float*)d_in[9];
    const float* Wn  = (const float*)d_in[10];
    const float* bn  = (const float*)d_in[11];
    const float* We  = (const float*)d_in[12];
    const float* be  = (const float*)d_in[13];
    const float* Wm  = (const float*)d_in[14];
    const float* bm  = (const float*)d_in[15];
    const float* Wlin = (const float*)d_in[16];
    const float* blin = (const float*)d_in[17];
    float* out = (float*)d_out;

    // workspace carve (256B aligned slices)
    char* p = (char*)d_ws;
    auto carve = [&](size_t bytes) { char* q = p; p += (bytes + 255) & ~(size_t)255; return q; };
    float* h     = (float*)carve((size_t)NNODES * NO * 4);        // 20.48 MB
    float* huv   = (float*)carve((size_t)NNODES * 768 * 4);       // 61.44 MB
    float* Wcat  = (float*)carve((size_t)NL * 768 * NO * 4);      // 22.02 MB
    float* bcat  = (float*)carve((size_t)NL * 768 * 4);
    float* xpad  = (float*)carve((size_t)NNODES * KPAD * 4);      // 5.12 MB
    int*   offs  = (int*)carve((size_t)(NNODES + 1) * 4);
    int*   cur   = (int*)carve((size_t)NNODES * 4);
    int*   srcp  = (int*)carve((size_t)NEDGES * 4);
    float* efp   = (float*)carve((size_t)NEDGES * 4);
    float* sums  = (float*)carve((size_t)NGRAPHS * NO * 4);

    const int* src = ei;
    const int* dst = ei + NEDGES;

    // CSR build
    hipMemsetAsync(cur, 0, (size_t)NNODES * 4, stream);
    k_hist<<<NEDGES / 256, 256, 0, stream>>>(dst, cur);
    k_scan<<<1, 256, 0, stream>>>(cur, offs);
    k_copy<<<(NNODES + 255) / 256, 256, 0, stream>>>(offs, cur, NNODES);
    k_fill<<<NEDGES / 256, 256, 0, stream>>>(src, dst, ef, cur, srcp, efp);

    // layer-0 padded input + composed per-layer weights
    k_padx<<<(NNODES * KPAD + 255) / 256, 256, 0, stream>>>(x, xpad);
    k_prep<<<NL * 768, 256, 0, stream>>>(Wn0, bn0, We0, be0, Wm0, bm0,
                                         Wn, bn, We, be, Wm, bm, Wcat, bcat);

    // 28 layers
    for (int l = 0; l < NL; ++l) {
        const float* Ain = (l == 0) ? xpad : h;
        int K = (l == 0) ? KPAD : NO;
        dim3 grid(768 / BN, (NNODES + BM - 1) / BM);
        k_gemm<<<grid, 256, 0, stream>>>(Ain, Wcat + (size_t)l * 768 * NO, bcat + (size_t)l * 768,
                                         huv, NNODES, K);
        k_edge<<<NNODES / 4, 256, 0, stream>>>(huv, offs, srcp, efp, h);
    }

    // mean-pool via sorted ranges, then tiny final GEMM
    hipMemsetAsync(sums, 0, (size_t)NGRAPHS * NO * 4, stream);
    dim3 pg(NGRAPHS, 8);
    k_pool2<<<pg, 256, 0, stream>>>(h, batch, sums);
    k_final<<<NGRAPHS, 512, 0, stream>>>(sums, batch, Wlin, blin, out);
}